// Round 6
// baseline (287.044 us; speedup 1.0000x reference)
//
#include <hip/hip_runtime.h>
#include <cstddef>

// Problem constants (fixed by setup_inputs)
#define BB 4
#define QQ 4096
#define MM 8
#define NN 21760

typedef __bf16 bf16_8 __attribute__((ext_vector_type(8)));
typedef __bf16 bf16_4 __attribute__((ext_vector_type(4)));
typedef float  floatx4 __attribute__((ext_vector_type(4)));

// Fragment-contiguous weight layout: element (n,k) of an [N][256] panel goes
// to offset (((n>>4)*8 + (k>>5))*4 + ((k>>3)&3))*128 + (n&15)*8 + (k&7).
// A wave's 64-lane frag load (lane = quad*16+l16 reads n=nf*16+l16,
// k=kk*32+quad*8..+7) is then 1 KB fully coalesced.
__host__ __device__ __forceinline__ int fragoff(int n, int k) {
    return (((n >> 4) * 8 + (k >> 5)) * 4 + ((k >> 3) & 3)) * 128 + ((n & 15) * 8) + (k & 7);
}

// ---------------------------------------------------------------------------
// Weight prep: fp32 W[K][N] -> bf16.
// Wt layout: Wval frag-layout [256 rows] | Wq frag-layout [384 rows] |
//            Wout n-major [256x256] (consumed by sampler_out phase 2).
// biasq[384] = [b_attn | b_off] fp32.
// ---------------------------------------------------------------------------
__global__ __launch_bounds__(256) void prep_weights(
    const float* __restrict__ Wv, const float* __restrict__ Wa,
    const float* __restrict__ Wo, const float* __restrict__ Wu,
    const float* __restrict__ ba, const float* __restrict__ bo,
    __bf16* __restrict__ Wt, float* __restrict__ biasq)
{
    const int gid = blockIdx.x * 256 + threadIdx.x;
    if (gid < 65536) {
        const int n = gid >> 8, k = gid & 255;
        Wt[fragoff(n, k)] = (__bf16)Wv[k * 256 + n];
    } else if (gid < 163840) {
        const int o = gid - 65536;
        const int n = o >> 8, k = o & 255;
        Wt[65536 + fragoff(n, k)] =
            (__bf16)(n < 128 ? Wa[k * 128 + n] : Wo[k * 256 + (n - 128)]);
    } else if (gid < 229376) {
        const int o = gid - 163840;
        const int n = o >> 8, k = o & 255;
        Wt[163840 + o] = (__bf16)Wu[k * 256 + n];   // n-major for sampler_out
    } else if (gid < 229760) {
        const int j = gid - 229376;
        biasq[j] = (j < 128) ? ba[j] : bo[j - 128];
    }
}

// ---------------------------------------------------------------------------
// Barrier-free streaming GEMM for v_p and q-proj.
// 512 threads = 8 waves; every wave computes a 32-token x 64-col tile with
// BOTH operands streamed to registers (no LDS staging, no K-loop barriers):
//   per kk (8 steps): 4 frag-coalesced weight loads (L2-hot) +
//   2x32B coalesced fp32 activation loads + cvt + 8 MFMAs.
// The compiler is free to pipeline loads across the whole loop (no
// s_barrier drain points) — this removes the stage->barrier->compute
// serial structure that pinned all previous variants at ~70 us.
// LDS (32 KB) is used only by the v_p epilogue to transpose the output so
// vpb is written as perfect 1KB-coalesced stores (was 5.6M scattered 8B).
//
// Blocks 0..1359   : v_p   (z = f/340, 64-token tile, 256 cols; 4x2 waves)
// Blocks 1360..1615: qproj cols 0..255,  64-token tile (4x2 waves)
// Blocks 1616..1743: qproj cols 256..383, 128-token tile (2x4 waves)
// ---------------------------------------------------------------------------
__global__ __launch_bounds__(512, 4) void gemm_vs(
    const float* __restrict__ v,
    const float* __restrict__ q,
    const __bf16* __restrict__ Wt,
    const float* __restrict__ b_val,
    const float* __restrict__ biasq,
    __bf16* __restrict__ vpb,          // [B,8,N,32] bf16
    float* __restrict__ gqp)           // [B*Q,384] fp32
{
    __shared__ __bf16 Ts[64][256];     // 32 KB, v_p transpose only

    const int tid  = threadIdx.x;
    const int lane = tid & 63;
    const int wave = tid >> 6;
    const int quad = lane >> 4;
    const int l16  = lane & 15;
    const int flat = blockIdx.x;

    if (flat < 1360) {
        // ---------------- v_p: 64 tokens x 256 cols -----------------------
        const int z      = flat / 340;
        const int tok0   = (flat - z * 340) * 64;
        const int colgrp = wave & 3;       // 4 x 64 cols
        const int tokgrp = wave >> 2;      // 2 x 32 tokens
        const int tok_base = tok0 + tokgrp * 32;
        const float* A0 = v + (size_t)z * NN * 256 + (size_t)(tok_base + l16) * 256;

        floatx4 acc[2][4] = {};
        #pragma unroll 2
        for (int kk = 0; kk < 8; ++kk) {
            bf16_8 wb[4];
            #pragma unroll
            for (int j = 0; j < 4; ++j) {
                const int nf = colgrp * 4 + j;
                wb[j] = *(const bf16_8*)(Wt + ((nf * 8 + kk) * 4 + quad) * 128 + l16 * 8);
            }
            bf16_8 fa[2];
            #pragma unroll
            for (int it = 0; it < 2; ++it) {
                const float* ap = A0 + it * 16 * 256 + kk * 32 + quad * 8;
                const float4 x0 = *(const float4*)ap;
                const float4 x1 = *(const float4*)(ap + 4);
                bf16_8 t;
                t[0] = (__bf16)x0.x; t[1] = (__bf16)x0.y;
                t[2] = (__bf16)x0.z; t[3] = (__bf16)x0.w;
                t[4] = (__bf16)x1.x; t[5] = (__bf16)x1.y;
                t[6] = (__bf16)x1.z; t[7] = (__bf16)x1.w;
                fa[it] = t;
            }
            #pragma unroll
            for (int it = 0; it < 2; ++it)
                #pragma unroll
                for (int j = 0; j < 4; ++j)
                    acc[it][j] = __builtin_amdgcn_mfma_f32_16x16x32_bf16(wb[j], fa[it], acc[it][j], 0, 0, 0);
        }

        // bias + bf16 + LDS transpose (16B-block XOR swizzle keyed on tok&7)
        #pragma unroll
        for (int j = 0; j < 4; ++j) {
            const int n0  = colgrp * 64 + j * 16 + quad * 4;
            const int blk = n0 >> 3;
            const float4 b4 = *(const float4*)(b_val + n0);
            #pragma unroll
            for (int it = 0; it < 2; ++it) {
                const int tok = tokgrp * 32 + it * 16 + l16;
                bf16_4 ob;
                ob[0] = (__bf16)(acc[it][j][0] + b4.x);
                ob[1] = (__bf16)(acc[it][j][1] + b4.y);
                ob[2] = (__bf16)(acc[it][j][2] + b4.z);
                ob[3] = (__bf16)(acc[it][j][3] + b4.w);
                *(bf16_4*)&Ts[tok][((blk ^ (tok & 7)) << 3) | (n0 & 7)] = ob;
            }
        }
        __syncthreads();

        // coalesced store: wave = one head's 4 KB run (64 tok x 64 B),
        // each instr writes a contiguous 1 KB (64 lanes x 16 B).
        const int head = tid >> 6;
        const size_t runbase = (((size_t)z * 8 + head) * NN + tok0) * 32;
        #pragma unroll
        for (int c = 0; c < 4; ++c) {
            const int tok = c * 16 + (lane >> 2);
            const int cb  = head * 4 + (lane & 3);
            const bf16_8 val = *(const bf16_8*)&Ts[tok][((cb ^ (tok & 7)) << 3)];
            *(bf16_8*)(vpb + runbase + c * 512 + lane * 8) = val;
        }
    } else {
        // ---------------- q-proj -------------------------------------------
        int tok_base, colbase;
        if (flat < 1616) {                       // Q1: 64 tok x cols 0..255
            const int idx = flat - 1360;
            colbase  = (wave & 3) * 64;
            tok_base = idx * 64 + (wave >> 2) * 32;
        } else {                                 // Q2: 128 tok x cols 256..383
            const int idx = flat - 1616;
            colbase  = 256 + (wave & 1) * 64;
            tok_base = idx * 128 + (wave >> 1) * 32;
        }
        const float* A0 = q + (size_t)(tok_base + l16) * 256;
        const __bf16* Wq = Wt + 65536;
        const int nfbase = colbase >> 4;

        floatx4 acc[2][4] = {};
        #pragma unroll 2
        for (int kk = 0; kk < 8; ++kk) {
            bf16_8 wb[4];
            #pragma unroll
            for (int j = 0; j < 4; ++j) {
                const int nf = nfbase + j;
                wb[j] = *(const bf16_8*)(Wq + ((nf * 8 + kk) * 4 + quad) * 128 + l16 * 8);
            }
            bf16_8 fa[2];
            #pragma unroll
            for (int it = 0; it < 2; ++it) {
                const float* ap = A0 + it * 16 * 256 + kk * 32 + quad * 8;
                const float4 x0 = *(const float4*)ap;
                const float4 x1 = *(const float4*)(ap + 4);
                bf16_8 t;
                t[0] = (__bf16)x0.x; t[1] = (__bf16)x0.y;
                t[2] = (__bf16)x0.z; t[3] = (__bf16)x0.w;
                t[4] = (__bf16)x1.x; t[5] = (__bf16)x1.y;
                t[6] = (__bf16)x1.z; t[7] = (__bf16)x1.w;
                fa[it] = t;
            }
            #pragma unroll
            for (int it = 0; it < 2; ++it)
                #pragma unroll
                for (int j = 0; j < 4; ++j)
                    acc[it][j] = __builtin_amdgcn_mfma_f32_16x16x32_bf16(wb[j], fa[it], acc[it][j], 0, 0, 0);
        }

        #pragma unroll
        for (int j = 0; j < 4; ++j) {
            const int n0 = colbase + j * 16 + quad * 4;
            const float4 b4 = *(const float4*)(biasq + n0);
            #pragma unroll
            for (int it = 0; it < 2; ++it) {
                const int token = tok_base + it * 16 + l16;
                float4 ot;
                ot.x = acc[it][j][0] + b4.x;
                ot.y = acc[it][j][1] + b4.y;
                ot.z = acc[it][j][2] + b4.z;
                ot.w = acc[it][j][3] + b4.w;
                *(float4*)(gqp + (size_t)token * 384 + n0) = ot;
            }
        }
    }
}

// ---------------------------------------------------------------------------
// Fused softmax + bilinear sampling + out-projection (unchanged, verified).
// 1024 blocks x 512 threads; block = 16 consecutive queries.
// ---------------------------------------------------------------------------
__device__ __forceinline__ float bflo(unsigned u) { return __uint_as_float(u << 16); }
__device__ __forceinline__ float bfhi(unsigned u) { return __uint_as_float(u & 0xffff0000u); }

__global__ __launch_bounds__(512) void sampler_out(
    const __bf16* __restrict__ vp,    // [B,8,N,32] bf16
    const float* __restrict__ gqp,    // [B*Q,384]
    const float* __restrict__ pref,   // [B*Q,4,2]
    const __bf16* __restrict__ Wout,  // [256][256] bf16 n-major
    const float* __restrict__ b_out,  // [256]
    float* __restrict__ out)          // [B*Q,256] fp32
{
    __shared__ __bf16 mids[16][256];  // 8 KB, XOR-swizzled

    const int t    = threadIdx.x;
    const int m    = t >> 6;        // wave = head
    const int lane = t & 63;
    const int s    = lane >> 2;     // sample 0..15
    const int c    = lane & 3;      // 16B chunk 0..3
    const int l    = s >> 2;        // level
    const int bq0  = blockIdx.x * 16;

    const int   Hi = 128 >> l;
    const float Hf = (float)Hi;
    const int   base = (l == 0) ? 0 : (l == 1) ? 16384 : (l == 2) ? 20480 : 21504;
    const int b2 = (lane >> 2) & 1, b3 = (lane >> 3) & 1, b4i = (lane >> 4) & 1;

    for (int qi = 0; qi < 16; ++qi) {
        const int bq = bq0 + qi;
        const int b  = bq >> 12;    // Q = 4096

        const float logit = gqp[(size_t)bq * 384 + m * 16 + s];
        const float e = __expf(logit);
        float sum = e;
        #pragma unroll
        for (int k = 4; k < 64; k <<= 1) sum += __shfl_xor(sum, k, 64);
        const float a = e * __builtin_amdgcn_rcpf(sum);

        const float2 off = *(const float2*)(gqp + (size_t)bq * 384 + 128 + (m * 16 + s) * 2);
        const float2 pr  = *(const float2*)(pref + (size_t)bq * 8 + l * 2);

        const float x = fmaf(pr.x, Hf, off.x - 0.5f);
        const float y = fmaf(pr.y, Hf, off.y - 0.5f);
        const float x0f = floorf(x), y0f = floorf(y);
        const float lx = x - x0f, ly = y - y0f;
        const int x0 = (int)x0f, y0 = (int)y0f;
        const int cx0 = min(max(x0, 0), Hi - 1), cx1 = min(max(x0 + 1, 0), Hi - 1);
        const int cy0 = min(max(y0, 0), Hi - 1), cy1 = min(max(y0 + 1, 0), Hi - 1);
        const bool vx0 = (x0 >= 0) && (x0 < Hi), vx1 = (x0 + 1 >= 0) && (x0 + 1 < Hi);
        const bool vy0 = (y0 >= 0) && (y0 < Hi), vy1 = (y0 + 1 >= 0) && (y0 + 1 < Hi);
        const float w00 = a * (1.f - lx) * (1.f - ly) * ((vx0 && vy0) ? 1.f : 0.f);
        const float w10 = a * lx * (1.f - ly) * ((vx1 && vy0) ? 1.f : 0.f);
        const float w01 = a * (1.f - lx) * ly * ((vx0 && vy1) ? 1.f : 0.f);
        const float w11 = a * lx * ly * ((vx1 && vy1) ? 1.f : 0.f);

        const __bf16* vbase = vp + ((size_t)b * 8 + m) * NN * 32;
        const uint4 u00 = *((const uint4*)(vbase + (size_t)(base + cy0 * Hi + cx0) * 32) + c);
        const uint4 u10 = *((const uint4*)(vbase + (size_t)(base + cy0 * Hi + cx1) * 32) + c);
        const uint4 u01 = *((const uint4*)(vbase + (size_t)(base + cy1 * Hi + cx0) * 32) + c);
        const uint4 u11 = *((const uint4*)(vbase + (size_t)(base + cy1 * Hi + cx1) * 32) + c);

        float f[8];
        f[0] = w00*bflo(u00.x) + w10*bflo(u10.x) + w01*bflo(u01.x) + w11*bflo(u11.x);
        f[1] = w00*bfhi(u00.x) + w10*bfhi(u10.x) + w01*bfhi(u01.x) + w11*bfhi(u11.x);
        f[2] = w00*bflo(u00.y) + w10*bflo(u10.y) + w01*bflo(u01.y) + w11*bflo(u11.y);
        f[3] = w00*bfhi(u00.y) + w10*bfhi(u10.y) + w01*bfhi(u01.y) + w11*bfhi(u11.y);
        f[4] = w00*bflo(u00.z) + w10*bflo(u10.z) + w01*bflo(u01.z) + w11*bflo(u11.z);
        f[5] = w00*bfhi(u00.z) + w10*bfhi(u10.z) + w01*bfhi(u01.z) + w11*bfhi(u11.z);
        f[6] = w00*bflo(u00.w) + w10*bflo(u10.w) + w01*bflo(u01.w) + w11*bflo(u11.w);
        f[7] = w00*bfhi(u00.w) + w10*bfhi(u10.w) + w01*bfhi(u01.w) + w11*bfhi(u11.w);

        #pragma unroll
        for (int j = 0; j < 4; ++j) {
            const float sel  = b2 ? f[j] : f[j + 4];
            const float recv = __shfl_xor(sel, 4, 64);
            f[j] = (b2 ? f[j + 4] : f[j]) + recv;
        }
        #pragma unroll
        for (int j = 0; j < 2; ++j) {
            const float sel  = b3 ? f[j] : f[j + 2];
            const float recv = __shfl_xor(sel, 8, 64);
            f[j] = (b3 ? f[j + 2] : f[j]) + recv;
        }
        {
            const float sel  = b4i ? f[0] : f[1];
            const float recv = __shfl_xor(sel, 16, 64);
            f[0] = (b4i ? f[1] : f[0]) + recv;
        }
        f[0] += __shfl_xor(f[0], 32, 64);

        if (!(lane & 32)) {
            const int chan = (c << 3) | (b2 << 2) | (b3 << 1) | b4i;
            const int cf   = m * 32 + chan;
            const int p = ((((cf >> 3) ^ (qi & 7)) << 3) | (cf & 7));
            mids[qi][p] = (__bf16)f[0];
        }
    }
    __syncthreads();

    const int quad = lane >> 4;
    const int l16  = lane & 15;

    bf16_8 wf[8][2];
    #pragma unroll
    for (int kk = 0; kk < 8; ++kk)
        #pragma unroll
        for (int j = 0; j < 2; ++j)
            wf[kk][j] = *(const bf16_8*)(Wout + (size_t)(m * 32 + j * 16 + l16) * 256
                                          + kk * 32 + quad * 8);

    floatx4 acc[2] = {};
    #pragma unroll
    for (int kk = 0; kk < 8; ++kk) {
        const bf16_8 af = *(const bf16_8*)&mids[l16][(((kk * 4 + quad) ^ (l16 & 7)) << 3)];
        #pragma unroll
        for (int j = 0; j < 2; ++j)
            acc[j] = __builtin_amdgcn_mfma_f32_16x16x32_bf16(wf[kk][j], af, acc[j], 0, 0, 0);
    }

    #pragma unroll
    for (int j = 0; j < 2; ++j) {
        const int n0 = m * 32 + j * 16 + quad * 4;
        const float4 b4 = *(const float4*)(b_out + n0);
        const int token = bq0 + l16;
        float4 o;
        o.x = acc[j][0] + b4.x;
        o.y = acc[j][1] + b4.y;
        o.z = acc[j][2] + b4.z;
        o.w = acc[j][3] + b4.w;
        *(float4*)(out + (size_t)token * 256 + n0) = o;
    }
}

extern "C" void kernel_launch(void* const* d_in, const int* in_sizes, int n_in,
                              void* d_out, int out_size, void* d_ws, size_t ws_size,
                              hipStream_t stream) {
    const float* q      = (const float*)d_in[0];
    const float* p      = (const float*)d_in[1];
    const float* v      = (const float*)d_in[2];
    const float* W_off  = (const float*)d_in[5];
    const float* b_off  = (const float*)d_in[6];
    const float* W_attn = (const float*)d_in[7];
    const float* b_attn = (const float*)d_in[8];
    const float* W_val  = (const float*)d_in[9];
    const float* b_val  = (const float*)d_in[10];
    const float* W_out  = (const float*)d_in[11];
    const float* b_out  = (const float*)d_in[12];
    float* out = (float*)d_out;

    // Workspace layout:
    //   gqp   : float [16384*384]
    //   biasq : float [384]
    //   mid   : bf16  [16384*256]   (unused; kept for layout stability)
    //   vpb   : bf16  [4*8*21760*32]
    //   Wt    : bf16  [229376]
    float*  gqp   = (float*)d_ws;
    float*  biasq = gqp + (size_t)16384 * 384;
    __bf16* mid   = (__bf16*)(biasq + 384);
    __bf16* vpb   = mid + (size_t)16384 * 256;
    __bf16* Wt    = vpb + (size_t)BB * 8 * NN * 32;
    __bf16* Wt_out = Wt + 163840;

    // 0) weights -> bf16 (frag layout for GEMM, n-major for sampler_out)
    prep_weights<<<898, 256, 0, stream>>>(W_val, W_attn, W_off, W_out, b_attn, b_off, Wt, biasq);

    // 1) barrier-free streaming v_p + q-proj: 1360 + 256 + 128 = 1744 blocks
    gemm_vs<<<1744, 512, 0, stream>>>(v, q, Wt, b_val, biasq, vpb, gqp);

    // 2) fused softmax + bilinear sampling + out-projection
    sampler_out<<<1024, 512, 0, stream>>>(vpb, gqp, p, Wt_out, b_out, out);
}

// Round 7
// 266.181 us; speedup vs baseline: 1.0784x; 1.0784x over previous
//
#include <hip/hip_runtime.h>
#include <cstddef>

// Problem constants (fixed by setup_inputs)
#define BB 4
#define QQ 4096
#define MM 8
#define NN 21760

typedef __bf16 bf16_8 __attribute__((ext_vector_type(8)));
typedef __bf16 bf16_4 __attribute__((ext_vector_type(4)));
typedef float  floatx4 __attribute__((ext_vector_type(4)));

// ---------------------------------------------------------------------------
// Weight prep: fp32 W[K][N] -> bf16 Wt[N][K]  (round-3 verified layout).
// Wt: Wval[256x256] | Wq[384x256] (attn 0..127 | off 128..383) | Wout[256x256]
// biasq[384] = [b_attn | b_off] fp32.
// ---------------------------------------------------------------------------
__global__ __launch_bounds__(256) void prep_weights(
    const float* __restrict__ Wv, const float* __restrict__ Wa,
    const float* __restrict__ Wo, const float* __restrict__ Wu,
    const float* __restrict__ ba, const float* __restrict__ bo,
    __bf16* __restrict__ Wt, float* __restrict__ biasq)
{
    const int gid = blockIdx.x * 256 + threadIdx.x;
    if (gid < 65536) {
        const int n = gid >> 8, k = gid & 255;
        Wt[gid] = (__bf16)Wv[k * 256 + n];
    } else if (gid < 163840) {
        const int o = gid - 65536;
        const int n = o >> 8, k = o & 255;
        Wt[gid] = (__bf16)(n < 128 ? Wa[k * 128 + n] : Wo[k * 256 + (n - 128)]);
    } else if (gid < 229376) {
        const int o = gid - 163840;
        const int n = o >> 8, k = o & 255;
        Wt[gid] = (__bf16)Wu[k * 256 + n];
    } else if (gid < 229760) {
        const int j = gid - 229376;
        biasq[j] = (j < 128) ? ba[j] : bo[j - 128];
    }
}

// ---------------------------------------------------------------------------
// v_p + q-proj GEMM with DMA staging (global_load_lds) — the one lever not
// yet tried against the 68-70us invariant.  32-token x 256-k fp32 tile
// (32 KB LDS -> 4 blocks/CU residency); fp32 goes STRAIGHT to LDS via
// global_load_lds width=16 (no VGPR round-trip, no cvt/ds_write on the
// staging path); fp32->bf16 conversion happens at fragment read (VALU,
// overlaps MFMA pipe).  16B-block XOR swizzle: LDS dest is linear (DMA
// constraint), the INVERSE swizzle is applied to the per-lane GLOBAL source
// address, the forward swizzle at read (both-sides rule).
//
// Blocks 0..511    : q-proj cols 0..255   (8 waves x 32 cols)
// Blocks 512..1023 : q-proj cols 256..383 (8 waves x 16 cols)
// Blocks 1024..3743: v_p (z = f/680, 680 tiles of 32 tokens, 8 w x 32 cols)
// ---------------------------------------------------------------------------
__global__ __launch_bounds__(512, 4) void gemm_vq2(
    const float* __restrict__ v,
    const float* __restrict__ q,
    const __bf16* __restrict__ Wt,
    const float* __restrict__ b_val,
    const float* __restrict__ biasq,   // [384]
    __bf16* __restrict__ vpb,          // [B,8,N,32] bf16
    float* __restrict__ gqp)           // [B*Q,384] fp32
{
    __shared__ float Asf[32][256];     // 32 KB fp32 activation tile

    const int tid  = threadIdx.x;
    const int lane = tid & 63;
    const int wave = tid >> 6;
    const int quad = lane >> 4;
    const int l16  = lane & 15;
    const int flat = blockIdx.x;

    // ---- job decode ----
    const float* Arow;
    const __bf16* Wpan;
    int tok0, colbase, z = 0;
    bool is_vp, two;
    if (flat < 512) {                       // Qa: cols 0..255
        Arow = q;  Wpan = Wt + 65536;
        tok0 = flat * 32;  colbase = wave * 32;
        is_vp = false;  two = true;
    } else if (flat < 1024) {               // Qb: cols 256..383
        Arow = q;  Wpan = Wt + 65536;
        tok0 = (flat - 512) * 32;  colbase = 256 + wave * 16;
        is_vp = false;  two = false;
    } else {                                // v_p
        const int f2 = flat - 1024;
        z = f2 / 680;
        tok0 = (f2 - z * 680) * 32;
        Arow = v + (size_t)z * NN * 256;  Wpan = Wt;
        colbase = wave * 32;
        is_vp = true;  two = true;
    }

    // ---- stage: 32 rows x 1KB via global_load_lds (wave w stages rows
    //      w*4..w*4+3; lane l's 16B lands at LDS block l, sourced from
    //      global block l ^ (r&7) => read-side swizzle is c ^ (r&7)) ----
    #pragma unroll
    for (int j = 0; j < 4; ++j) {
        const int r = wave * 4 + j;
        const float* gp = Arow + (size_t)(tok0 + r) * 256 + ((lane ^ (r & 7)) << 2);
        __builtin_amdgcn_global_load_lds(
            (const __attribute__((address_space(1))) void*)gp,
            (__attribute__((address_space(3))) void*)&Asf[r][0],
            16, 0, 0);
    }

    // ---- weights -> VGPRs (n-major, as round 3) ----
    bf16_8 wf[8][2];
    #pragma unroll
    for (int kk = 0; kk < 8; ++kk) {
        wf[kk][0] = *(const bf16_8*)(Wpan + (size_t)(colbase + l16) * 256 + kk * 32 + quad * 8);
        if (two)
            wf[kk][1] = *(const bf16_8*)(Wpan + (size_t)(colbase + 16 + l16) * 256 + kk * 32 + quad * 8);
    }

    __syncthreads();   // drains DMA (vmcnt 0) — tile + weights ready

    // ---- MFMA: fragments read fp32 (swizzled blocks) + cvt to bf16 ----
    floatx4 acc[2][2] = {};
    #pragma unroll
    for (int kk = 0; kk < 8; ++kk) {
        bf16_8 af[2];
        #pragma unroll
        for (int it = 0; it < 2; ++it) {
            const int rr = it * 16 + l16;
            const int sw = rr & 7;
            const int c0 = kk * 8 + quad * 2;             // 16B-block index
            const float4 x0 = *(const float4*)&Asf[rr][((c0 ^ sw) << 2)];
            const float4 x1 = *(const float4*)&Asf[rr][(((c0 + 1) ^ sw) << 2)];
            bf16_8 t;
            t[0] = (__bf16)x0.x; t[1] = (__bf16)x0.y;
            t[2] = (__bf16)x0.z; t[3] = (__bf16)x0.w;
            t[4] = (__bf16)x1.x; t[5] = (__bf16)x1.y;
            t[6] = (__bf16)x1.z; t[7] = (__bf16)x1.w;
            af[it] = t;
        }
        #pragma unroll
        for (int it = 0; it < 2; ++it) {
            acc[0][it] = __builtin_amdgcn_mfma_f32_16x16x32_bf16(wf[kk][0], af[it], acc[0][it], 0, 0, 0);
            if (two)
                acc[1][it] = __builtin_amdgcn_mfma_f32_16x16x32_bf16(wf[kk][1], af[it], acc[1][it], 0, 0, 0);
        }
    }

    // ---- epilogue (formulas verbatim from round 3) ----
    if (is_vp) {
        #pragma unroll
        for (int j = 0; j < 2; ++j) {
            const int n0 = colbase + j * 16 + quad * 4;
            const float4 b4 = *(const float4*)(b_val + n0);
            const int mh = n0 >> 5, dd = n0 & 31;
            #pragma unroll
            for (int it = 0; it < 2; ++it) {
                const int token = tok0 + it * 16 + l16;
                bf16_4 ob;
                ob[0] = (__bf16)(acc[j][it][0] + b4.x);
                ob[1] = (__bf16)(acc[j][it][1] + b4.y);
                ob[2] = (__bf16)(acc[j][it][2] + b4.z);
                ob[3] = (__bf16)(acc[j][it][3] + b4.w);
                *(bf16_4*)(vpb + (((size_t)z * 8 + mh) * NN + token) * 32 + dd) = ob;
            }
        }
    } else {
        #pragma unroll
        for (int j = 0; j < 2; ++j) {
            if (j == 1 && !two) break;
            const int n0 = colbase + j * 16 + quad * 4;
            const float4 b4 = *(const float4*)(biasq + n0);
            #pragma unroll
            for (int it = 0; it < 2; ++it) {
                const int token = tok0 + it * 16 + l16;
                float4 ot;
                ot.x = acc[j][it][0] + b4.x;
                ot.y = acc[j][it][1] + b4.y;
                ot.z = acc[j][it][2] + b4.z;
                ot.w = acc[j][it][3] + b4.w;
                *(float4*)(gqp + (size_t)token * 384 + n0) = ot;
            }
        }
    }
}

// ---------------------------------------------------------------------------
// Weight-stationary bf16 MFMA GEMM (out-projection; round-3 verbatim).
// ---------------------------------------------------------------------------
template<typename AT, int NCB, int MODE>
__global__ __launch_bounds__(512, 4) void gemm_ws(
    const AT* __restrict__ A,
    const __bf16* __restrict__ Wn,     // [NCTOT][256] bf16 (n-major)
    const float* __restrict__ bias,    // [NCTOT] fp32
    void* __restrict__ Cout,
    int tokens, int ldc)
{
    constexpr int F  = NCB / 8;
    constexpr int NJ = F / 16;

    const int z    = blockIdx.z;
    const int col0 = blockIdx.x * NCB;
    const AT* Ab   = A + (size_t)z * tokens * 256;
    const __bf16* Wb = Wn + (size_t)col0 * 256;

    __shared__ __bf16 As[64][256];

    const int tid  = threadIdx.x;
    const int lane = tid & 63;
    const int wave = tid >> 6;
    const int quad = lane >> 4;
    const int l16  = lane & 15;
    const int wave_f = wave * F;

    const int token0 = blockIdx.y * 64;
    if (sizeof(AT) == 4) {
        const float* Af = (const float*)Ab;
        #pragma unroll
        for (int c = 0; c < 8; ++c) {
            const int cid = c * 512 + tid;
            const int r   = cid >> 6;
            const int kc  = (cid & 63) * 4;
            const float4 av = *(const float4*)(Af + (size_t)(token0 + r) * 256 + kc);
            bf16_4 w;
            w[0] = (__bf16)av.x; w[1] = (__bf16)av.y;
            w[2] = (__bf16)av.z; w[3] = (__bf16)av.w;
            const int col = ((((kc >> 3) ^ (r & 7)) << 3) | (kc & 7));
            *(bf16_4*)&As[r][col] = w;
        }
    } else {
        const __bf16* Ah = (const __bf16*)Ab;
        #pragma unroll
        for (int c = 0; c < 4; ++c) {
            const int cid = c * 512 + tid;
            const int r   = cid >> 5;
            const int kc  = (cid & 31) * 8;
            const bf16_8 av = *(const bf16_8*)(Ah + (size_t)(token0 + r) * 256 + kc);
            const int col = (((kc >> 3) ^ (r & 7)) << 3);
            *(bf16_8*)&As[r][col] = av;
        }
    }

    bf16_8 wf[8][NJ];
    #pragma unroll
    for (int kk = 0; kk < 8; ++kk)
        #pragma unroll
        for (int j = 0; j < NJ; ++j)
            wf[kk][j] = *(const bf16_8*)(Wb + (size_t)(wave_f + j * 16 + l16) * 256
                                          + kk * 32 + quad * 8);
    __syncthreads();

    floatx4 acc[NJ][4] = {};
    #pragma unroll
    for (int kk = 0; kk < 8; ++kk) {
        bf16_8 af[4];
        #pragma unroll
        for (int it = 0; it < 4; ++it)
            af[it] = *(const bf16_8*)&As[it * 16 + l16]
                                       [(((kk * 4 + quad) ^ (l16 & 7)) << 3)];
        #pragma unroll
        for (int j = 0; j < NJ; ++j)
            #pragma unroll
            for (int it = 0; it < 4; ++it)
                acc[j][it] = __builtin_amdgcn_mfma_f32_16x16x32_bf16(wf[kk][j], af[it], acc[j][it], 0, 0, 0);
    }

    #pragma unroll
    for (int j = 0; j < NJ; ++j) {
        const int n0 = col0 + wave_f + j * 16 + quad * 4;
        const float4 b4 = *(const float4*)(bias + n0);
        #pragma unroll
        for (int it = 0; it < 4; ++it) {
            const int token = token0 + it * 16 + l16;
            const float v0 = acc[j][it][0] + b4.x;
            const float v1 = acc[j][it][1] + b4.y;
            const float v2 = acc[j][it][2] + b4.z;
            const float v3 = acc[j][it][3] + b4.w;
            if (MODE == 0) {
                float4 o; o.x = v0; o.y = v1; o.z = v2; o.w = v3;
                *(float4*)((float*)Cout + ((size_t)z * tokens + token) * ldc + n0) = o;
            } else {
                const int mh = n0 >> 5, dd = n0 & 31;
                bf16_4 ob;
                ob[0] = (__bf16)v0; ob[1] = (__bf16)v1; ob[2] = (__bf16)v2; ob[3] = (__bf16)v3;
                *(bf16_4*)((__bf16*)Cout + (((size_t)z * 8 + mh) * NN + token) * 32 + dd) = ob;
            }
        }
    }
}

// ---------------------------------------------------------------------------
// Fused softmax + bilinear sampling (round-3 verbatim): 16384 blocks x 512,
// one query per block (max gather TLP — round 4 proved the 16-query serial
// fusion loses 15us).
// ---------------------------------------------------------------------------
__device__ __forceinline__ float bflo(unsigned u) { return __uint_as_float(u << 16); }
__device__ __forceinline__ float bfhi(unsigned u) { return __uint_as_float(u & 0xffff0000u); }

__global__ __launch_bounds__(512) void sampler(
    const __bf16* __restrict__ vp,    // [B,8,N,32] bf16
    const float* __restrict__ gqp,    // [B*Q,384]
    const float* __restrict__ pref,   // [B*Q,4,2]
    __bf16* __restrict__ mid)         // [B*Q,256] bf16
{
    const int t    = threadIdx.x;
    const int m    = t >> 6;
    const int lane = t & 63;
    const int s    = lane >> 2;
    const int c    = lane & 3;
    const int l    = s >> 2;
    const int bq   = blockIdx.x;
    const int b    = bq >> 12;

    const int   Hi = 128 >> l;
    const float Hf = (float)Hi;
    const int   base = (l == 0) ? 0 : (l == 1) ? 16384 : (l == 2) ? 20480 : 21504;

    const float logit = gqp[(size_t)bq * 384 + m * 16 + s];
    const float e = __expf(logit);
    float sum = e;
    #pragma unroll
    for (int k = 4; k < 64; k <<= 1) sum += __shfl_xor(sum, k, 64);
    const float a = e * __builtin_amdgcn_rcpf(sum);

    const float2 off = *(const float2*)(gqp + (size_t)bq * 384 + 128 + (m * 16 + s) * 2);
    const float2 pr  = *(const float2*)(pref + (size_t)bq * 8 + l * 2);

    const float x = fmaf(pr.x, Hf, off.x - 0.5f);
    const float y = fmaf(pr.y, Hf, off.y - 0.5f);
    const float x0f = floorf(x), y0f = floorf(y);
    const float lx = x - x0f, ly = y - y0f;
    const int x0 = (int)x0f, y0 = (int)y0f;
    const int cx0 = min(max(x0, 0), Hi - 1), cx1 = min(max(x0 + 1, 0), Hi - 1);
    const int cy0 = min(max(y0, 0), Hi - 1), cy1 = min(max(y0 + 1, 0), Hi - 1);
    const bool vx0 = (x0 >= 0) && (x0 < Hi), vx1 = (x0 + 1 >= 0) && (x0 + 1 < Hi);
    const bool vy0 = (y0 >= 0) && (y0 < Hi), vy1 = (y0 + 1 >= 0) && (y0 + 1 < Hi);
    const float w00 = a * (1.f - lx) * (1.f - ly) * ((vx0 && vy0) ? 1.f : 0.f);
    const float w10 = a * lx * (1.f - ly) * ((vx1 && vy0) ? 1.f : 0.f);
    const float w01 = a * (1.f - lx) * ly * ((vx0 && vy1) ? 1.f : 0.f);
    const float w11 = a * lx * ly * ((vx1 && vy1) ? 1.f : 0.f);

    const __bf16* vbase = vp + ((size_t)b * 8 + m) * NN * 32;
    const uint4 u00 = *((const uint4*)(vbase + (size_t)(base + cy0 * Hi + cx0) * 32) + c);
    const uint4 u10 = *((const uint4*)(vbase + (size_t)(base + cy0 * Hi + cx1) * 32) + c);
    const uint4 u01 = *((const uint4*)(vbase + (size_t)(base + cy1 * Hi + cx0) * 32) + c);
    const uint4 u11 = *((const uint4*)(vbase + (size_t)(base + cy1 * Hi + cx1) * 32) + c);

    float f[8];
    f[0] = w00*bflo(u00.x) + w10*bflo(u10.x) + w01*bflo(u01.x) + w11*bflo(u11.x);
    f[1] = w00*bfhi(u00.x) + w10*bfhi(u10.x) + w01*bfhi(u01.x) + w11*bfhi(u11.x);
    f[2] = w00*bflo(u00.y) + w10*bflo(u10.y) + w01*bflo(u01.y) + w11*bflo(u11.y);
    f[3] = w00*bfhi(u00.y) + w10*bfhi(u10.y) + w01*bfhi(u01.y) + w11*bfhi(u11.y);
    f[4] = w00*bflo(u00.z) + w10*bflo(u10.z) + w01*bflo(u01.z) + w11*bflo(u11.z);
    f[5] = w00*bfhi(u00.z) + w10*bfhi(u10.z) + w01*bfhi(u01.z) + w11*bfhi(u11.z);
    f[6] = w00*bflo(u00.w) + w10*bflo(u10.w) + w01*bflo(u01.w) + w11*bflo(u11.w);
    f[7] = w00*bfhi(u00.w) + w10*bfhi(u10.w) + w01*bfhi(u01.w) + w11*bfhi(u11.w);

    const int b2 = (lane >> 2) & 1, b3 = (lane >> 3) & 1, b4i = (lane >> 4) & 1;
    #pragma unroll
    for (int j = 0; j < 4; ++j) {
        const float sel  = b2 ? f[j] : f[j + 4];
        const float recv = __shfl_xor(sel, 4, 64);
        f[j] = (b2 ? f[j + 4] : f[j]) + recv;
    }
    #pragma unroll
    for (int j = 0; j < 2; ++j) {
        const float sel  = b3 ? f[j] : f[j + 2];
        const float recv = __shfl_xor(sel, 8, 64);
        f[j] = (b3 ? f[j + 2] : f[j]) + recv;
    }
    {
        const float sel  = b4i ? f[0] : f[1];
        const float recv = __shfl_xor(sel, 16, 64);
        f[0] = (b4i ? f[1] : f[0]) + recv;
    }
    f[0] += __shfl_xor(f[0], 32, 64);

    if (!(lane & 32)) {
        const int chan = (c << 3) | (b2 << 2) | (b3 << 1) | b4i;
        mid[(size_t)bq * 256 + m * 32 + chan] = (__bf16)f[0];
    }
}

extern "C" void kernel_launch(void* const* d_in, const int* in_sizes, int n_in,
                              void* d_out, int out_size, void* d_ws, size_t ws_size,
                              hipStream_t stream) {
    const float* q      = (const float*)d_in[0];
    const float* p      = (const float*)d_in[1];
    const float* v      = (const float*)d_in[2];
    const float* W_off  = (const float*)d_in[5];
    const float* b_off  = (const float*)d_in[6];
    const float* W_attn = (const float*)d_in[7];
    const float* b_attn = (const float*)d_in[8];
    const float* W_val  = (const float*)d_in[9];
    const float* b_val  = (const float*)d_in[10];
    const float* W_out  = (const float*)d_in[11];
    const float* b_out  = (const float*)d_in[12];
    float* out = (float*)d_out;

    // Workspace layout (round-3):
    //   gqp   : float [16384*384]
    //   biasq : float [384]
    //   mid   : bf16  [16384*256]
    //   vpb   : bf16  [4*8*21760*32]
    //   Wt    : bf16  [229376]
    float*  gqp   = (float*)d_ws;
    float*  biasq = gqp + (size_t)16384 * 384;
    __bf16* mid   = (__bf16*)(biasq + 384);
    __bf16* vpb   = mid + (size_t)16384 * 256;
    __bf16* Wt    = vpb + (size_t)BB * 8 * NN * 32;
    __bf16* Wt_out = Wt + 163840;

    // 0) weights -> bf16 transposed
    prep_weights<<<898, 256, 0, stream>>>(W_val, W_attn, W_off, W_out, b_attn, b_off, Wt, biasq);

    // 1) v_p + q-proj with DMA staging: 512 + 512 + 2720 = 3744 blocks
    gemm_vq2<<<3744, 512, 0, stream>>>(v, q, Wt, b_val, biasq, vpb, gqp);

    // 2) softmax + bilinear sampling -> mid bf16 [B*Q,256]
    sampler<<<BB * QQ, 512, 0, stream>>>(vpb, gqp, p, mid);

    // 3) out = mid @ W_out + b_out  (2 slices -> 512 blocks)
    {
        dim3 grid(2, 256, 1);
        gemm_ws<__bf16, 128, 0><<<grid, 512, 0, stream>>>(mid, Wt_out, b_out, out, BB * QQ, 256);
    }
}

// Round 10
// 244.406 us; speedup vs baseline: 1.1745x; 1.0891x over previous
//
#include <hip/hip_runtime.h>
#include <cstddef>

// Problem constants (fixed by setup_inputs)
#define BB 4
#define QQ 4096
#define MM 8
#define NN 21760

typedef __bf16 bf16_8 __attribute__((ext_vector_type(8)));
typedef __bf16 bf16_4 __attribute__((ext_vector_type(4)));
typedef float  floatx4 __attribute__((ext_vector_type(4)));

// ---------------------------------------------------------------------------
// Weight prep: fp32 W[K][N] -> bf16 Wt[N][K]  (round-3 verified layout).
// Wt: Wval[256x256] | Wq[384x256] (attn 0..127 | off 128..383) | Wout[256x256]
// biasq[384] = [b_attn | b_off] fp32.
// ---------------------------------------------------------------------------
__global__ __launch_bounds__(256) void prep_weights(
    const float* __restrict__ Wv, const float* __restrict__ Wa,
    const float* __restrict__ Wo, const float* __restrict__ Wu,
    const float* __restrict__ ba, const float* __restrict__ bo,
    __bf16* __restrict__ Wt, float* __restrict__ biasq)
{
    const int gid = blockIdx.x * 256 + threadIdx.x;
    if (gid < 65536) {
        const int n = gid >> 8, k = gid & 255;
        Wt[gid] = (__bf16)Wv[k * 256 + n];
    } else if (gid < 163840) {
        const int o = gid - 65536;
        const int n = o >> 8, k = o & 255;
        Wt[gid] = (__bf16)(n < 128 ? Wa[k * 128 + n] : Wo[k * 256 + (n - 128)]);
    } else if (gid < 229376) {
        const int o = gid - 163840;
        const int n = o >> 8, k = o & 255;
        Wt[gid] = (__bf16)Wu[k * 256 + n];
    } else if (gid < 229760) {
        const int j = gid - 229376;
        biasq[j] = (j < 128) ? ba[j] : bo[j - 128];
    }
}

// ---------------------------------------------------------------------------
// Fused v_p + q-proj GEMM, round-3 structure + hoisted staging.
// NOTE: __launch_bounds__(512) with NO min-waves arg — the (512,3) variant
// killed two containers (suspected toolchain issue); default bounds give the
// allocator freedom to keep all 8 staged float4s + the weight panel resident
// (~130 regs live), which is the experiment: more outstanding HBM loads per
// wave (previous builds at VGPR 40-60 pinned read BW at ~1.9 TB/s).
// Blocks 0..767: q-proj (3 slices x 128 cols); 768..2127: v_p (256 cols).
// ---------------------------------------------------------------------------
__global__ __launch_bounds__(512) void gemm_vq3(
    const float* __restrict__ v,
    const float* __restrict__ q,
    const __bf16* __restrict__ Wt,     // weight table base (Wval | Wq | Wout)
    const float* __restrict__ b_val,
    const float* __restrict__ biasq,   // [384]
    __bf16* __restrict__ vpb,          // [B,8,N,32] bf16
    float* __restrict__ gqp)           // [B*Q,384] fp32
{
    // XOR-swizzled activation tile: element (r, k) lives at column
    // ((k>>3) ^ (r&7))<<3 | (k&7).  32 KB (64 x 256 bf16).
    __shared__ __bf16 As[64][256];

    const int tid  = threadIdx.x;
    const int lane = tid & 63;
    const int wave = tid >> 6;
    const int quad = lane >> 4;
    const int l16  = lane & 15;
    const int flat = blockIdx.x;

    if (flat >= 768) {
        // ---------------- v_p: z in [0,4), 340 token tiles, 256 cols -------
        const int f2     = flat - 768;
        const int z      = f2 / 340;
        const int token0 = (f2 - z * 340) * 64;
        const float* Af  = v + (size_t)z * NN * 256;

        // stage loads: ALL EIGHT issued first (32 VGPR live, deep vmem queue)
        float4 a4[8];
        #pragma unroll
        for (int c = 0; c < 8; ++c) {
            const int cid = c * 512 + tid;
            const int r   = cid >> 6;
            const int kc  = (cid & 63) * 4;
            a4[c] = *(const float4*)(Af + (size_t)(token0 + r) * 256 + kc);
        }

        // weight panel -> VGPRs (issued behind the stage loads)
        bf16_8 wf[8][2];
        #pragma unroll
        for (int kk = 0; kk < 8; ++kk)
            #pragma unroll
            for (int j = 0; j < 2; ++j)
                wf[kk][j] = *(const bf16_8*)(Wt + (size_t)(wave * 32 + j * 16 + l16) * 256
                                              + kk * 32 + quad * 8);

        // cvt + swizzled LDS write (drains a4 in issue order)
        #pragma unroll
        for (int c = 0; c < 8; ++c) {
            const int cid = c * 512 + tid;
            const int r   = cid >> 6;
            const int kc  = (cid & 63) * 4;
            bf16_4 w;
            w[0] = (__bf16)a4[c].x; w[1] = (__bf16)a4[c].y;
            w[2] = (__bf16)a4[c].z; w[3] = (__bf16)a4[c].w;
            const int col = ((((kc >> 3) ^ (r & 7)) << 3) | (kc & 7));
            *(bf16_4*)&As[r][col] = w;
        }
        __syncthreads();

        floatx4 acc[2][4] = {};
        #pragma unroll
        for (int kk = 0; kk < 8; ++kk) {
            bf16_8 af[4];
            #pragma unroll
            for (int it = 0; it < 4; ++it)
                af[it] = *(const bf16_8*)&As[it * 16 + l16]
                                           [(((kk * 4 + quad) ^ (l16 & 7)) << 3)];
            #pragma unroll
            for (int j = 0; j < 2; ++j)
                #pragma unroll
                for (int it = 0; it < 4; ++it)
                    acc[j][it] = __builtin_amdgcn_mfma_f32_16x16x32_bf16(wf[kk][j], af[it], acc[j][it], 0, 0, 0);
        }

        #pragma unroll
        for (int j = 0; j < 2; ++j) {
            const int n0 = wave * 32 + j * 16 + quad * 4;
            const float4 b4 = *(const float4*)(b_val + n0);
            const int mh = n0 >> 5, dd = n0 & 31;
            #pragma unroll
            for (int it = 0; it < 4; ++it) {
                const int token = token0 + it * 16 + l16;
                bf16_4 ob;
                ob[0] = (__bf16)(acc[j][it][0] + b4.x);
                ob[1] = (__bf16)(acc[j][it][1] + b4.y);
                ob[2] = (__bf16)(acc[j][it][2] + b4.z);
                ob[3] = (__bf16)(acc[j][it][3] + b4.w);
                *(bf16_4*)(vpb + (((size_t)z * 8 + mh) * NN + token) * 32 + dd) = ob;
            }
        }
    } else {
        // ---------------- q-proj: 3 slices x 256 token tiles, 128 cols -----
        const int o      = flat;
        const int slice  = o >> 8;           // 0..2
        const int token0 = (o & 255) * 64;
        const int col0   = slice * 128;
        const __bf16* Wb = Wt + 65536 + (size_t)col0 * 256;   // Wq rows

        float4 a4[8];
        #pragma unroll
        for (int c = 0; c < 8; ++c) {
            const int cid = c * 512 + tid;
            const int r   = cid >> 6;
            const int kc  = (cid & 63) * 4;
            a4[c] = *(const float4*)(q + (size_t)(token0 + r) * 256 + kc);
        }

        bf16_8 wf[8];
        #pragma unroll
        for (int kk = 0; kk < 8; ++kk)
            wf[kk] = *(const bf16_8*)(Wb + (size_t)(wave * 16 + l16) * 256
                                       + kk * 32 + quad * 8);

        #pragma unroll
        for (int c = 0; c < 8; ++c) {
            const int cid = c * 512 + tid;
            const int r   = cid >> 6;
            const int kc  = (cid & 63) * 4;
            bf16_4 w;
            w[0] = (__bf16)a4[c].x; w[1] = (__bf16)a4[c].y;
            w[2] = (__bf16)a4[c].z; w[3] = (__bf16)a4[c].w;
            const int col = ((((kc >> 3) ^ (r & 7)) << 3) | (kc & 7));
            *(bf16_4*)&As[r][col] = w;
        }
        __syncthreads();

        floatx4 acc[4] = {};
        #pragma unroll
        for (int kk = 0; kk < 8; ++kk) {
            bf16_8 af[4];
            #pragma unroll
            for (int it = 0; it < 4; ++it)
                af[it] = *(const bf16_8*)&As[it * 16 + l16]
                                           [(((kk * 4 + quad) ^ (l16 & 7)) << 3)];
            #pragma unroll
            for (int it = 0; it < 4; ++it)
                acc[it] = __builtin_amdgcn_mfma_f32_16x16x32_bf16(wf[kk], af[it], acc[it], 0, 0, 0);
        }

        const int n0 = col0 + wave * 16 + quad * 4;
        const float4 b4 = *(const float4*)(biasq + n0);
        #pragma unroll
        for (int it = 0; it < 4; ++it) {
            const int token = token0 + it * 16 + l16;
            float4 ot;
            ot.x = acc[it][0] + b4.x;
            ot.y = acc[it][1] + b4.y;
            ot.z = acc[it][2] + b4.z;
            ot.w = acc[it][3] + b4.w;
            *(float4*)(gqp + (size_t)token * 384 + n0) = ot;
        }
    }
}

// ---------------------------------------------------------------------------
// Weight-stationary bf16 MFMA GEMM (out-projection; round-3 verbatim).
// ---------------------------------------------------------------------------
template<typename AT, int NCB, int MODE>
__global__ __launch_bounds__(512, 4) void gemm_ws(
    const AT* __restrict__ A,
    const __bf16* __restrict__ Wn,     // [NCTOT][256] bf16 (n-major)
    const float* __restrict__ bias,    // [NCTOT] fp32
    void* __restrict__ Cout,
    int tokens, int ldc)
{
    constexpr int F  = NCB / 8;
    constexpr int NJ = F / 16;

    const int z    = blockIdx.z;
    const int col0 = blockIdx.x * NCB;
    const AT* Ab   = A + (size_t)z * tokens * 256;
    const __bf16* Wb = Wn + (size_t)col0 * 256;

    __shared__ __bf16 As[64][256];

    const int tid  = threadIdx.x;
    const int lane = tid & 63;
    const int wave = tid >> 6;
    const int quad = lane >> 4;
    const int l16  = lane & 15;
    const int wave_f = wave * F;

    const int token0 = blockIdx.y * 64;
    if (sizeof(AT) == 4) {
        const float* Af = (const float*)Ab;
        #pragma unroll
        for (int c = 0; c < 8; ++c) {
            const int cid = c * 512 + tid;
            const int r   = cid >> 6;
            const int kc  = (cid & 63) * 4;
            const float4 av = *(const float4*)(Af + (size_t)(token0 + r) * 256 + kc);
            bf16_4 w;
            w[0] = (__bf16)av.x; w[1] = (__bf16)av.y;
            w[2] = (__bf16)av.z; w[3] = (__bf16)av.w;
            const int col = ((((kc >> 3) ^ (r & 7)) << 3) | (kc & 7));
            *(bf16_4*)&As[r][col] = w;
        }
    } else {
        const __bf16* Ah = (const __bf16*)Ab;
        #pragma unroll
        for (int c = 0; c < 4; ++c) {
            const int cid = c * 512 + tid;
            const int r   = cid >> 5;
            const int kc  = (cid & 31) * 8;
            const bf16_8 av = *(const bf16_8*)(Ah + (size_t)(token0 + r) * 256 + kc);
            const int col = (((kc >> 3) ^ (r & 7)) << 3);
            *(bf16_8*)&As[r][col] = av;
        }
    }

    bf16_8 wf[8][NJ];
    #pragma unroll
    for (int kk = 0; kk < 8; ++kk)
        #pragma unroll
        for (int j = 0; j < NJ; ++j)
            wf[kk][j] = *(const bf16_8*)(Wb + (size_t)(wave_f + j * 16 + l16) * 256
                                          + kk * 32 + quad * 8);
    __syncthreads();

    floatx4 acc[NJ][4] = {};
    #pragma unroll
    for (int kk = 0; kk < 8; ++kk) {
        bf16_8 af[4];
        #pragma unroll
        for (int it = 0; it < 4; ++it)
            af[it] = *(const bf16_8*)&As[it * 16 + l16]
                                       [(((kk * 4 + quad) ^ (l16 & 7)) << 3)];
        #pragma unroll
        for (int j = 0; j < NJ; ++j)
            #pragma unroll
            for (int it = 0; it < 4; ++it)
                acc[j][it] = __builtin_amdgcn_mfma_f32_16x16x32_bf16(wf[kk][j], af[it], acc[j][it], 0, 0, 0);
    }

    #pragma unroll
    for (int j = 0; j < NJ; ++j) {
        const int n0 = col0 + wave_f + j * 16 + quad * 4;
        const float4 b4 = *(const float4*)(bias + n0);
        #pragma unroll
        for (int it = 0; it < 4; ++it) {
            const int token = token0 + it * 16 + l16;
            const float v0 = acc[j][it][0] + b4.x;
            const float v1 = acc[j][it][1] + b4.y;
            const float v2 = acc[j][it][2] + b4.z;
            const float v3 = acc[j][it][3] + b4.w;
            if (MODE == 0) {
                float4 o; o.x = v0; o.y = v1; o.z = v2; o.w = v3;
                *(float4*)((float*)Cout + ((size_t)z * tokens + token) * ldc + n0) = o;
            } else {
                const int mh = n0 >> 5, dd = n0 & 31;
                bf16_4 ob;
                ob[0] = (__bf16)v0; ob[1] = (__bf16)v1; ob[2] = (__bf16)v2; ob[3] = (__bf16)v3;
                *(bf16_4*)((__bf16*)Cout + (((size_t)z * 8 + mh) * NN + token) * 32 + dd) = ob;
            }
        }
    }
}

// ---------------------------------------------------------------------------
// Fused softmax + bilinear sampling (round-3 verbatim): 16384 blocks x 512,
// one query per block (max gather TLP).
// ---------------------------------------------------------------------------
__device__ __forceinline__ float bflo(unsigned u) { return __uint_as_float(u << 16); }
__device__ __forceinline__ float bfhi(unsigned u) { return __uint_as_float(u & 0xffff0000u); }

__global__ __launch_bounds__(512) void sampler(
    const __bf16* __restrict__ vp,    // [B,8,N,32] bf16
    const float* __restrict__ gqp,    // [B*Q,384]
    const float* __restrict__ pref,   // [B*Q,4,2]
    __bf16* __restrict__ mid)         // [B*Q,256] bf16
{
    const int t    = threadIdx.x;
    const int m    = t >> 6;
    const int lane = t & 63;
    const int s    = lane >> 2;
    const int c    = lane & 3;
    const int l    = s >> 2;
    const int bq   = blockIdx.x;
    const int b    = bq >> 12;

    const int   Hi = 128 >> l;
    const float Hf = (float)Hi;
    const int   base = (l == 0) ? 0 : (l == 1) ? 16384 : (l == 2) ? 20480 : 21504;

    const float logit = gqp[(size_t)bq * 384 + m * 16 + s];
    const float e = __expf(logit);
    float sum = e;
    #pragma unroll
    for (int k = 4; k < 64; k <<= 1) sum += __shfl_xor(sum, k, 64);
    const float a = e * __builtin_amdgcn_rcpf(sum);

    const float2 off = *(const float2*)(gqp + (size_t)bq * 384 + 128 + (m * 16 + s) * 2);
    const float2 pr  = *(const float2*)(pref + (size_t)bq * 8 + l * 2);

    const float x = fmaf(pr.x, Hf, off.x - 0.5f);
    const float y = fmaf(pr.y, Hf, off.y - 0.5f);
    const float x0f = floorf(x), y0f = floorf(y);
    const float lx = x - x0f, ly = y - y0f;
    const int x0 = (int)x0f, y0 = (int)y0f;
    const int cx0 = min(max(x0, 0), Hi - 1), cx1 = min(max(x0 + 1, 0), Hi - 1);
    const int cy0 = min(max(y0, 0), Hi - 1), cy1 = min(max(y0 + 1, 0), Hi - 1);
    const bool vx0 = (x0 >= 0) && (x0 < Hi), vx1 = (x0 + 1 >= 0) && (x0 + 1 < Hi);
    const bool vy0 = (y0 >= 0) && (y0 < Hi), vy1 = (y0 + 1 >= 0) && (y0 + 1 < Hi);
    const float w00 = a * (1.f - lx) * (1.f - ly) * ((vx0 && vy0) ? 1.f : 0.f);
    const float w10 = a * lx * (1.f - ly) * ((vx1 && vy0) ? 1.f : 0.f);
    const float w01 = a * (1.f - lx) * ly * ((vx0 && vy1) ? 1.f : 0.f);
    const float w11 = a * lx * ly * ((vx1 && vy1) ? 1.f : 0.f);

    const __bf16* vbase = vp + ((size_t)b * 8 + m) * NN * 32;
    const uint4 u00 = *((const uint4*)(vbase + (size_t)(base + cy0 * Hi + cx0) * 32) + c);
    const uint4 u10 = *((const uint4*)(vbase + (size_t)(base + cy0 * Hi + cx1) * 32) + c);
    const uint4 u01 = *((const uint4*)(vbase + (size_t)(base + cy1 * Hi + cx0) * 32) + c);
    const uint4 u11 = *((const uint4*)(vbase + (size_t)(base + cy1 * Hi + cx1) * 32) + c);

    float f[8];
    f[0] = w00*bflo(u00.x) + w10*bflo(u10.x) + w01*bflo(u01.x) + w11*bflo(u11.x);
    f[1] = w00*bfhi(u00.x) + w10*bfhi(u10.x) + w01*bfhi(u01.x) + w11*bfhi(u11.x);
    f[2] = w00*bflo(u00.y) + w10*bflo(u10.y) + w01*bflo(u01.y) + w11*bflo(u11.y);
    f[3] = w00*bfhi(u00.y) + w10*bfhi(u10.y) + w01*bfhi(u01.y) + w11*bfhi(u11.y);
    f[4] = w00*bflo(u00.z) + w10*bflo(u10.z) + w01*bflo(u01.z) + w11*bflo(u11.z);
    f[5] = w00*bfhi(u00.z) + w10*bfhi(u10.z) + w01*bfhi(u01.z) + w11*bfhi(u11.z);
    f[6] = w00*bflo(u00.w) + w10*bflo(u10.w) + w01*bflo(u01.w) + w11*bflo(u11.w);
    f[7] = w00*bfhi(u00.w) + w10*bfhi(u10.w) + w01*bfhi(u01.w) + w11*bfhi(u11.w);

    const int b2 = (lane >> 2) & 1, b3 = (lane >> 3) & 1, b4i = (lane >> 4) & 1;
    #pragma unroll
    for (int j = 0; j < 4; ++j) {
        const float sel  = b2 ? f[j] : f[j + 4];
        const float recv = __shfl_xor(sel, 4, 64);
        f[j] = (b2 ? f[j + 4] : f[j]) + recv;
    }
    #pragma unroll
    for (int j = 0; j < 2; ++j) {
        const float sel  = b3 ? f[j] : f[j + 2];
        const float recv = __shfl_xor(sel, 8, 64);
        f[j] = (b3 ? f[j + 2] : f[j]) + recv;
    }
    {
        const float sel  = b4i ? f[0] : f[1];
        const float recv = __shfl_xor(sel, 16, 64);
        f[0] = (b4i ? f[1] : f[0]) + recv;
    }
    f[0] += __shfl_xor(f[0], 32, 64);

    if (!(lane & 32)) {
        const int chan = (c << 3) | (b2 << 2) | (b3 << 1) | b4i;
        mid[(size_t)bq * 256 + m * 32 + chan] = (__bf16)f[0];
    }
}

extern "C" void kernel_launch(void* const* d_in, const int* in_sizes, int n_in,
                              void* d_out, int out_size, void* d_ws, size_t ws_size,
                              hipStream_t stream) {
    const float* q      = (const float*)d_in[0];
    const float* p      = (const float*)d_in[1];
    const float* v      = (const float*)d_in[2];
    const float* W_off  = (const float*)d_in[5];
    const float* b_off  = (const float*)d_in[6];
    const float* W_attn = (const float*)d_in[7];
    const float* b_attn = (const float*)d_in[8];
    const float* W_val  = (const float*)d_in[9];
    const float* b_val  = (const float*)d_in[10];
    const float* W_out  = (const float*)d_in[11];
    const float* b_out  = (const float*)d_in[12];
    float* out = (float*)d_out;

    // Workspace layout (round-3):
    //   gqp   : float [16384*384]
    //   biasq : float [384]
    //   mid   : bf16  [16384*256]
    //   vpb   : bf16  [4*8*21760*32]
    //   Wt    : bf16  [229376]
    float*  gqp   = (float*)d_ws;
    float*  biasq = gqp + (size_t)16384 * 384;
    __bf16* mid   = (__bf16*)(biasq + 384);
    __bf16* vpb   = mid + (size_t)16384 * 256;
    __bf16* Wt    = vpb + (size_t)BB * 8 * NN * 32;
    __bf16* Wt_out = Wt + 163840;

    // 0) weights -> bf16 transposed
    prep_weights<<<898, 256, 0, stream>>>(W_val, W_attn, W_off, W_out, b_attn, b_off, Wt, biasq);

    // 1) fused v_p + q-proj (hoisted staging): 768 + 1360 = 2128 blocks
    gemm_vq3<<<2128, 512, 0, stream>>>(v, q, Wt, b_val, biasq, vpb, gqp);

    // 2) softmax + bilinear sampling -> mid bf16 [B*Q,256]
    sampler<<<BB * QQ, 512, 0, stream>>>(vpb, gqp, p, mid);

    // 3) out = mid @ W_out + b_out  (2 slices -> 512 blocks)
    {
        dim3 grid(2, 256, 1);
        gemm_ws<__bf16, 128, 0><<<grid, 512, 0, stream>>>(mid, Wt_out, b_out, out, BB * QQ, 256);
    }
}